// Round 20
// baseline (462.577 us; speedup 1.0000x reference)
//
#include <hip/hip_runtime.h>
#include <hip/hip_bf16.h>
#include <math.h>

#define HW   64
#define NPIX 4096
#define CCH  128
#define KC   1152   // 9*C
#define KF   2304   // 9*256 (final conv K)
#define SCALEF 10.0f

typedef __attribute__((ext_vector_type(8))) short bf16x8;
typedef __attribute__((ext_vector_type(4))) float f32x4;
typedef __attribute__((ext_vector_type(4))) unsigned short u16x4;

__device__ inline void gload_lds16(const void* g, void* l) {
    __builtin_amdgcn_global_load_lds(
        (const __attribute__((address_space(1))) unsigned int*)g,
        (__attribute__((address_space(3))) unsigned int*)l, 16, 0, 0);
}

__device__ inline f32x4 ld4u(const float* p) {
    f32x4 v; __builtin_memcpy(&v, p, 16); return v;
}

// LDS tile layout (both GEMMs): slot (r,g) at byte r*64 + ((g ^ ((r>>1)&3))<<4).
// Staged via global_load_lds with PRE-SWIZZLED SOURCE (linear LDS dest, rule #21);
// read with the same involution -> conflict-free on both sides.
#define SWZ_OFF(r, g) ((r) * 64 + ((((g) ^ (((r) >> 1) & 3))) << 4))

// ---------------- build Pbf[n,1152] AND Pt[1152,4096]; batch via grid.y ----------
__global__ void k_build(const float* __restrict__ x, __hip_bfloat16* __restrict__ P,
                        __hip_bfloat16* __restrict__ Pt, size_t sP, size_t sPt, int b0) {
    const int b = b0 + blockIdx.y;
    P += (size_t)blockIdx.y * sP; Pt += (size_t)blockIdx.y * sPt;
    int idx = blockIdx.x * blockDim.x + threadIdx.x;
    if (idx < NPIX * KC) {
        int n = idx / KC, t = idx - n * KC;
        int u = t / 384, v = (t / 128) % 3, c = t & 127;
        int h = n >> 6, w = n & 63;
        int hh = h + u - 1, ww = w + v - 1;
        float val = 0.f;
        if (hh >= 0 && hh < HW && ww >= 0 && ww < HW)
            val = x[((size_t)(b * NPIX) + hh * HW + ww) * CCH + c];
        P[(size_t)n * KC + t] = __float2bfloat16(val);
    } else {
        int i2 = idx - NPIX * KC;
        int j = i2 >> 12, k = i2 & 4095;
        int u = j / 384, v = (j / 128) % 3, c = j & 127;
        int h = k >> 6, w = k & 63;
        int hh = h + u - 1, ww = w + v - 1;
        float val = 0.f;
        if (hh >= 0 && hh < HW && ww >= 0 && ww < HW)
            val = x[((size_t)(b * NPIX) + hh * HW + ww) * CCH + c];
        Pt[i2] = __float2bfloat16(val);
    }
}

// ---------------- per-patch norm + mask validity; batch via grid.y ----------------
__global__ void k_normmm(const __hip_bfloat16* __restrict__ P, size_t sP,
                         float* __restrict__ cn, size_t sCn,
                         const float* __restrict__ mask, float* __restrict__ mmv, int b0) {
    const int b = b0 + blockIdx.y;
    P += (size_t)blockIdx.y * sP; cn += (size_t)blockIdx.y * sCn;
    mmv += (size_t)blockIdx.y * sCn;
    int n = blockIdx.x;
    int tid = threadIdx.x;
    float s = 0.f;
    for (int t = tid; t < KC; t += 256) {
        float v = __bfloat162float(P[(size_t)n * KC + t]);
        s += v * v;
    }
    __shared__ float red[256];
    red[tid] = s; __syncthreads();
    for (int st = 128; st > 0; st >>= 1) {
        if (tid < st) red[tid] += red[tid + st];
        __syncthreads();
    }
    if (tid == 0) cn[n] = fmaxf(sqrtf(red[0]), 1e-4f);
    if (tid == 64) {
        int h = n >> 6, w = n & 63;
        float ms = 0.f;
        for (int u = 0; u < 3; u++)
            for (int v = 0; v < 3; v++) {
                int hh = h + u - 1, ww = w + v - 1;
                if (hh >= 0 && hh < HW && ww >= 0 && ww < HW)
                    ms += mask[(size_t)b * NPIX + hh * HW + ww];
            }
        mmv[n] = ((ms / 9.0f) == 1.0f) ? 1.0f : 0.0f;
    }
}

// ---------------- prep: zero page + all weight splits ----------------
__global__ void k_prep(const float* __restrict__ Wc, const float* __restrict__ W2,
                       const float* __restrict__ W1,
                       __hip_bfloat16* __restrict__ wtc_h, __hip_bfloat16* __restrict__ wtc_l,
                       __hip_bfloat16* __restrict__ wt2_h, __hip_bfloat16* __restrict__ wt2_l,
                       __hip_bfloat16* __restrict__ w1t_h, __hip_bfloat16* __restrict__ w1t_l,
                       float* __restrict__ zp) {
    int idx = blockIdx.x * blockDim.x + threadIdx.x;
    const int NWS = 2 * 128 * KF;
    if (idx < NWS) {
        int m = idx / (128 * KF);
        int rem = idx - m * 128 * KF;
        int j = rem / KF, k = rem - j * KF;
        const float* src = m ? W2 : Wc;
        float v = src[(size_t)k * 128 + j];
        __hip_bfloat16 hi = __float2bfloat16(v);
        __hip_bfloat16 lo = __float2bfloat16(v - __bfloat162float(hi));
        (m ? wt2_h : wtc_h)[(size_t)j * KF + k] = hi;
        (m ? wt2_l : wtc_l)[(size_t)j * KF + k] = lo;
    } else if (idx < NWS + 128 * 256) {
        int i2 = idx - NWS;
        int j = i2 >> 8, k = i2 & 255;
        float v = W1[(size_t)k * 128 + j];
        __hip_bfloat16 hi = __float2bfloat16(v);
        __hip_bfloat16 lo = __float2bfloat16(v - __bfloat162float(hi));
        w1t_h[(size_t)j * 256 + k] = hi;
        w1t_l[(size_t)j * 256 + k] = lo;
    } else if (idx < NWS + 128 * 256 + 64) {
        zp[idx - NWS - 128 * 256] = 0.f;
    }
}

// ---------------- GEMM1 symmetric: upper-triangle tiles, BK=32, preswz gload -----
__global__ __launch_bounds__(256) void k_gemm_sym(
    const __hip_bfloat16* __restrict__ A, float* __restrict__ C,
    const float* __restrict__ colnorm, size_t sA, size_t sC, size_t sCn) {
    __shared__ __align__(16) __hip_bfloat16 As[2][128 * 32];
    __shared__ __align__(16) __hip_bfloat16 Bs[2][128 * 32];
    A += (size_t)blockIdx.y * sA; C += (size_t)blockIdx.y * sC;
    colnorm += (size_t)blockIdx.y * sCn;
    const int tid = threadIdx.x;
    const int l = tid & 63;
    const int wid = tid >> 6;
    const int wr = wid >> 1, wc = wid & 1;
    const int lane16 = l & 15, kgrp = l >> 4;
    const int id0 = blockIdx.x;
    int t = (id0 & 7) * 66 + (id0 >> 3);
    int ti = 0;
    while (t >= 32 - ti) { t -= 32 - ti; ti++; }
    const int tj = ti + t;
    const int p0 = ti * 128, q0 = tj * 128;
    const int lr = l >> 2;
    const int lc = l & 3;

    f32x4 acc[16];
    f32x4 zf; zf[0] = 0.f; zf[1] = 0.f; zf[2] = 0.f; zf[3] = 0.f;
    #pragma unroll
    for (int i = 0; i < 16; i++) acc[i] = zf;

    auto stage = [&](int buf, int k0) {
        #pragma unroll
        for (int tt = 0; tt < 2; tt++) {
            int r0 = wid * 32 + tt * 16;
            int gr = r0 + lr;
            int sc = (lc ^ ((gr >> 1) & 3)) * 8;
            gload_lds16(A + (size_t)(p0 + gr) * KC + k0 + sc,
                        (char*)As[buf] + r0 * 64);
            gload_lds16(A + (size_t)(q0 + gr) * KC + k0 + sc,
                        (char*)Bs[buf] + r0 * 64);
        }
    };

    const int nst = KC >> 5;
    stage(0, 0);
    __syncthreads();
    int cur = 0;
    for (int s = 0; s < nst; ++s) {
        if (s + 1 < nst) stage(cur ^ 1, (s + 1) << 5);
        const char* Ab = (const char*)As[cur];
        const char* Bb = (const char*)Bs[cur];
        bf16x8 af[4], bg[4];
        #pragma unroll
        for (int mi = 0; mi < 4; mi++) {
            int row = wr * 64 + mi * 16 + lane16;
            af[mi] = *(const bf16x8*)(Ab + SWZ_OFF(row, kgrp));
        }
        #pragma unroll
        for (int ni = 0; ni < 4; ni++) {
            int row = wc * 64 + ni * 16 + lane16;
            bg[ni] = *(const bf16x8*)(Bb + SWZ_OFF(row, kgrp));
        }
        #pragma unroll
        for (int mi = 0; mi < 4; mi++)
            #pragma unroll
            for (int ni = 0; ni < 4; ni++)
                acc[mi * 4 + ni] = __builtin_amdgcn_mfma_f32_16x16x32_bf16(
                    af[mi], bg[ni], acc[mi * 4 + ni], 0, 0, 0);
        __syncthreads();
        cur ^= 1;
    }

    float invq[4];
    #pragma unroll
    for (int ni = 0; ni < 4; ni++)
        invq[ni] = 1.0f / colnorm[q0 + wc * 64 + ni * 16 + lane16];
    float invp[4][4];
    #pragma unroll
    for (int mi = 0; mi < 4; mi++) {
        int rbase = p0 + wr * 64 + mi * 16 + kgrp * 4;
        #pragma unroll
        for (int j = 0; j < 4; j++)
            invp[mi][j] = 1.0f / colnorm[rbase + j];
    }
    #pragma unroll
    for (int mi = 0; mi < 4; mi++) {
        int rbase = p0 + wr * 64 + mi * 16 + kgrp * 4;
        #pragma unroll
        for (int ni = 0; ni < 4; ni++) {
            int col = q0 + wc * 64 + ni * 16 + lane16;
            f32x4 v = acc[mi * 4 + ni];
            #pragma unroll
            for (int j = 0; j < 4; j++)
                __builtin_nontemporal_store(v[j] * invq[ni],
                                            &C[(size_t)(rbase + j) * NPIX + col]);
            if (ti != tj) {
                f32x4 tv;
                tv[0] = v[0] * invp[mi][0]; tv[1] = v[1] * invp[mi][1];
                tv[2] = v[2] * invp[mi][2]; tv[3] = v[3] * invp[mi][3];
                __builtin_nontemporal_store(tv,
                    (f32x4*)&C[(size_t)col * NPIX + rbase]);
            }
        }
    }
}

// ---------------- GEMM2: 128x128, BK=32, preswz gload, batch-z -------------------
__global__ __launch_bounds__(256) void k_mfma_gemm(
    const __hip_bfloat16* __restrict__ A, const __hip_bfloat16* __restrict__ B,
    float* __restrict__ C, int Ka, int ldc, size_t sA, size_t sB, size_t sC) {
    __shared__ __align__(16) __hip_bfloat16 As[2][128 * 32];
    __shared__ __align__(16) __hip_bfloat16 Bs[2][128 * 32];
    const int zb = blockIdx.z;
    A += (size_t)zb * sA; B += (size_t)zb * sB; C += (size_t)zb * sC;
    const int tid = threadIdx.x;
    const int l = tid & 63;
    const int wid = tid >> 6;
    const int wr = wid >> 1, wc = wid & 1;
    const int lane16 = l & 15, kgrp = l >> 4;
    const int gx = gridDim.x;
    const int nwg = gx * gridDim.y;
    const int id0 = blockIdx.y * gx + blockIdx.x;
    const int swzid = (id0 & 7) * (nwg >> 3) + (id0 >> 3);
    const int p0 = (swzid / gx) * 128, q0 = (swzid % gx) * 128;
    const int lr = l >> 2;
    const int lc = l & 3;

    f32x4 acc[16];
    f32x4 zf; zf[0] = 0.f; zf[1] = 0.f; zf[2] = 0.f; zf[3] = 0.f;
    #pragma unroll
    for (int i = 0; i < 16; i++) acc[i] = zf;

    auto stage = [&](int buf, int k0) {
        #pragma unroll
        for (int tt = 0; tt < 2; tt++) {
            int r0 = wid * 32 + tt * 16;
            int gr = r0 + lr;
            int sc = (lc ^ ((gr >> 1) & 3)) * 8;
            gload_lds16(A + (size_t)(p0 + gr) * Ka + k0 + sc,
                        (char*)As[buf] + r0 * 64);
            gload_lds16(B + (size_t)(q0 + gr) * Ka + k0 + sc,
                        (char*)Bs[buf] + r0 * 64);
        }
    };

    const int nst = Ka >> 5;
    stage(0, 0);
    __syncthreads();
    int cur = 0;
    for (int s = 0; s < nst; ++s) {
        if (s + 1 < nst) stage(cur ^ 1, (s + 1) << 5);
        const char* Ab = (const char*)As[cur];
        const char* Bb = (const char*)Bs[cur];
        bf16x8 af[4], bg[4];
        #pragma unroll
        for (int mi = 0; mi < 4; mi++) {
            int row = wr * 64 + mi * 16 + lane16;
            af[mi] = *(const bf16x8*)(Ab + SWZ_OFF(row, kgrp));
        }
        #pragma unroll
        for (int ni = 0; ni < 4; ni++) {
            int row = wc * 64 + ni * 16 + lane16;
            bg[ni] = *(const bf16x8*)(Bb + SWZ_OFF(row, kgrp));
        }
        #pragma unroll
        for (int mi = 0; mi < 4; mi++)
            #pragma unroll
            for (int ni = 0; ni < 4; ni++)
                acc[mi * 4 + ni] = __builtin_amdgcn_mfma_f32_16x16x32_bf16(
                    af[mi], bg[ni], acc[mi * 4 + ni], 0, 0, 0);
        __syncthreads();
        cur ^= 1;
    }

    #pragma unroll
    for (int mi = 0; mi < 4; mi++) {
        int rbase = p0 + wr * 64 + mi * 16 + kgrp * 4;
        #pragma unroll
        for (int ni = 0; ni < 4; ni++) {
            int col = q0 + wc * 64 + ni * 16 + lane16;
            f32x4 v = acc[mi * 4 + ni];
            #pragma unroll
            for (int j = 0; j < 4; j++)
                __builtin_nontemporal_store(v[j],
                                            &C[(size_t)(rbase + j) * ldc + col]);
        }
    }
}

// ---------------- fuse + mask + softmax; shuffle reductions; batch via grid.y ----
__global__ __launch_bounds__(256) void k_fusesm(const float* __restrict__ S, size_t sS,
                                                const float* __restrict__ mmv, size_t sM,
                                                __hip_bfloat16* __restrict__ Y, size_t sY) {
    S += (size_t)blockIdx.y * sS; mmv += (size_t)blockIdx.y * sM;
    Y += (size_t)blockIdx.y * sY;
    int blk = blockIdx.x;
    int p = ((blk & 7) << 9) | (blk >> 3);
    int tid = threadIdx.x;
    __shared__ float wredA[4], wredB[4];
    int cmp = ((p & 63) << 6) | (p >> 6);
    const float* rowp[3][3];
    #pragma unroll
    for (int ei = 0; ei < 3; ei++)
        #pragma unroll
        for (int di = 0; di < 3; di++) {
            int cp2 = cmp + ei - 1;
            const float* rp = nullptr;
            if (cp2 >= 0 && cp2 < NPIX) {
                int prm = ((cp2 & 63) << 6) | (cp2 >> 6);
                int pa = prm + di - 1;
                if (pa >= 0 && pa < NPIX) rp = S + (size_t)pa * NPIX;
            }
            rowp[ei][di] = rp;
        }

    f32x4 zv[4];
    float lmax = -1e30f;
    #pragma unroll
    for (int qi = 0; qi < 4; qi++) {
        const int q0 = (qi << 10) + (tid << 2);
        f32x4 acc; acc[0] = 0.f; acc[1] = 0.f; acc[2] = 0.f; acc[3] = 0.f;
        if (q0 >= 68 && q0 <= 4024) {
            #pragma unroll
            for (int ei = 0; ei < 3; ei++)
                #pragma unroll
                for (int di = 0; di < 3; di++) {
                    const float* rp = rowp[ei][di];
                    if (!rp) continue;
                    f32x4 v = ld4u(rp + q0 + (ei - 1) * 64 + (di - 1));
                    acc[0] += v[0]; acc[1] += v[1]; acc[2] += v[2]; acc[3] += v[3];
                }
        } else {
            #pragma unroll
            for (int j = 0; j < 4; j++) {
                int q = q0 + j;
                int cmq = ((q & 63) << 6) | (q >> 6);
                float a = 0.f;
                #pragma unroll
                for (int ei = 0; ei < 3; ei++) {
                    int cq2 = cmq + ei - 1;
                    if (cq2 < 0 || cq2 >= NPIX) continue;
                    int qrm = ((cq2 & 63) << 6) | (cq2 >> 6);
                    #pragma unroll
                    for (int di = 0; di < 3; di++) {
                        int qa = qrm + di - 1;
                        const float* rp = rowp[ei][di];
                        if (rp && qa >= 0 && qa < NPIX) a += rp[qa];
                    }
                }
                acc[j] = a;
            }
        }
        f32x4 m4 = *(const f32x4*)(mmv + q0);
        #pragma unroll
        for (int j = 0; j < 4; j++) {
            float zz = acc[j] * m4[j] * SCALEF;
            zv[qi][j] = zz;
            lmax = fmaxf(lmax, zz);
        }
    }

    #pragma unroll
    for (int off = 32; off >= 1; off >>= 1)
        lmax = fmaxf(lmax, __shfl_xor(lmax, off, 64));
    if ((tid & 63) == 0) wredA[tid >> 6] = lmax;
    __syncthreads();
    float gmax = fmaxf(fmaxf(wredA[0], wredA[1]), fmaxf(wredA[2], wredA[3]));

    float lsum = 0.f;
    #pragma unroll
    for (int qi = 0; qi < 4; qi++)
        #pragma unroll
        for (int j = 0; j < 4; j++) {
            float e = __expf(zv[qi][j] - gmax);
            zv[qi][j] = e;
            lsum += e;
        }
    #pragma unroll
    for (int off = 32; off >= 1; off >>= 1)
        lsum += __shfl_xor(lsum, off, 64);
    if ((tid & 63) == 0) wredB[tid >> 6] = lsum;
    __syncthreads();
    float invs = 1.0f / (((wredB[0] + wredB[1]) + (wredB[2] + wredB[3])));

    #pragma unroll
    for (int qi = 0; qi < 4; qi++) {
        const int q0 = (qi << 10) + (tid << 2);
        f32x4 m4 = *(const f32x4*)(mmv + q0);
        u16x4 tmp;
        #pragma unroll
        for (int j = 0; j < 4; j++) {
            __hip_bfloat16 bv = __float2bfloat16(zv[qi][j] * invs * m4[j]);
            tmp[j] = *(unsigned short*)&bv;
        }
        __builtin_nontemporal_store(tmp, (u16x4*)(Y + (size_t)p * NPIX + q0));
    }
}

// ---------------- deconv gather + concat with x -> hi/lo bf16 ----------------
__global__ void k_deconv(const float* __restrict__ O2, const float* __restrict__ x,
                         __hip_bfloat16* __restrict__ ych, __hip_bfloat16* __restrict__ ycl,
                         size_t sO2) {
    int idx = blockIdx.x * blockDim.x + threadIdx.x;
    int b = idx >> 19;
    int loc = idx & ((1 << 19) - 1);
    int p = loc >> 7, c = loc & 127;
    int h = p >> 6, w = p & 63;
    const float* O2b = O2 + (size_t)b * sO2;
    float acc = 0.f;
    #pragma unroll
    for (int u = 0; u < 3; u++) {
        int hh = h + 1 - u;
        if (hh < 0 || hh >= HW) continue;
        #pragma unroll
        for (int v = 0; v < 3; v++) {
            int ww = w + 1 - v;
            if (ww < 0 || ww >= HW) continue;
            acc += O2b[(size_t)(hh * HW + ww) * KC + (u * 3 + v) * CCH + c];
        }
    }
    float xv = x[((size_t)b * NPIX + p) * CCH + c];
    size_t base = (size_t)b * NPIX * 256 + (size_t)p * 256;
    __hip_bfloat16 ah = __float2bfloat16(acc);
    __hip_bfloat16 xh = __float2bfloat16(xv);
    ych[base + c] = ah;
    ych[base + 128 + c] = xh;
    ycl[base + c] = __float2bfloat16(acc - __bfloat162float(ah));
    ycl[base + 128 + c] = __float2bfloat16(xv - __bfloat162float(xh));
}

// ---------------- final conv via split-bf16 MFMA, W1 gate folded in ----------------
__global__ __launch_bounds__(256) void k_final_mfma(
    const __hip_bfloat16* __restrict__ ych, const __hip_bfloat16* __restrict__ ycl,
    const __hip_bfloat16* __restrict__ wtc_h, const __hip_bfloat16* __restrict__ wtc_l,
    const __hip_bfloat16* __restrict__ wt2_h, const __hip_bfloat16* __restrict__ wt2_l,
    const __hip_bfloat16* __restrict__ w1t_h, const __hip_bfloat16* __restrict__ w1t_l,
    const float* __restrict__ bc, const float* __restrict__ b1,
    const float* __restrict__ b2, const float* __restrict__ zpage,
    float* __restrict__ outp) {
    __shared__ __align__(16) char As_h[2048], As_l[2048];
    __shared__ __align__(16) char Bs_h[32768], Bs_l[32768];
    const int tid = threadIdx.x;
    const int lane = tid & 63, wv = tid >> 6;
    const int lane16 = lane & 15, kgrp = lane >> 4;
    const int gblk = blockIdx.x;
    const int b = gblk >> 8;
    const int p0l = (gblk & 255) * 16;
    const __hip_bfloat16* ybh = ych + (size_t)b * NPIX * 256;
    const __hip_bfloat16* ybl = ycl + (size_t)b * NPIX * 256;
    const int srow8 = lane >> 3;
    const int c16 = lane & 7;
    const int swc = c16 ^ srow8;

    const int arow = ((wv & 1) << 3) + srow8;
    const int apr = p0l + arow;
    const int ah_ = apr >> 6, aw_ = apr & 63;
    char* const a_ldst = ((wv >> 1) ? As_l : As_h) + ((wv & 1) << 10);
    const __hip_bfloat16* const a_base = (wv >> 1) ? ybl : ybh;

    const char* bsrc_h[8];
    const char* bsrc_l[8];
    #pragma unroll
    for (int r = 0; r < 8; r++) {
        int q = r * 4 + wv;
        int row = q * 8 + srow8;
        const __hip_bfloat16* mh = (row < 128) ? (wtc_h + (size_t)row * KF)
                                               : (wt2_h + (size_t)(row - 128) * KF);
        const __hip_bfloat16* ml = (row < 128) ? (wtc_l + (size_t)row * KF)
                                               : (wt2_l + (size_t)(row - 128) * KF);
        bsrc_h[r] = (const char*)(mh + swc * 8);
        bsrc_l[r] = (const char*)(ml + swc * 8);
    }

    f32x4 acc[4];
    f32x4 zf; zf[0] = 0.f; zf[1] = 0.f; zf[2] = 0.f; zf[3] = 0.f;
    #pragma unroll
    for (int f = 0; f < 4; f++) acc[f] = zf;

    for (int it = 0; it < 36; ++it) {
        const int k0 = it * 64;
        const int tap = k0 >> 8, i0 = k0 & 255;
        const int di = tap / 3, dj = tap - di * 3;
        {
            int hh = ah_ + di - 1, ww = aw_ + dj - 1;
            const void* src;
            if (hh >= 0 && hh < HW && ww >= 0 && ww < HW)
                src = a_base + ((size_t)(hh * HW + ww) * 256 + i0 + swc * 8);
            else
                src = (const char*)zpage + c16 * 16;
            gload_lds16(src, a_ldst);
        }
        #pragma unroll
        for (int r = 0; r < 8; r++) {
            int q = r * 4 + wv;
            gload_lds16(bsrc_h[r] + (size_t)it * 128, Bs_h + (q << 10));
            gload_lds16(bsrc_l[r] + (size_t)it * 128, Bs_l + (q << 10));
        }
        __syncthreads();
        #pragma unroll
        for (int kh = 0; kh < 2; kh++) {
            const int chunk = kgrp + 4 * kh;
            const int abyte = lane16 * 128 + ((chunk ^ (lane16 & 7)) << 4);
            bf16x8 ah = *(const bf16x8*)(As_h + abyte);
            bf16x8 al = *(const bf16x8*)(As_l + abyte);
            #pragma unroll
            for (int f = 0; f < 4; f++) {
                int brow = ((f < 2) ? 0 : 128) + wv * 32 + ((f & 1) << 4) + lane16;
                int bbyte = brow * 128 + ((chunk ^ (brow & 7)) << 4);
                bf16x8 bh = *(const bf16x8*)(Bs_h + bbyte);
                bf16x8 bl = *(const bf16x8*)(Bs_l + bbyte);
                acc[f] = __builtin_amdgcn_mfma_f32_16x16x32_bf16(ah, bh, acc[f], 0, 0, 0);
                acc[f] = __builtin_amdgcn_mfma_f32_16x16x32_bf16(ah, bl, acc[f], 0, 0, 0);
                acc[f] = __builtin_amdgcn_mfma_f32_16x16x32_bf16(al, bh, acc[f], 0, 0, 0);
            }
        }
        __syncthreads();
    }

    f32x4 acc1[2];
    acc1[0] = zf; acc1[1] = zf;
    for (int ki = 0; ki < 4; ++ki) {
        gload_lds16(a_base + ((size_t)(ah_ * HW + aw_) * 256 + ki * 64 + swc * 8), a_ldst);
        #pragma unroll
        for (int r = 0; r < 4; r++) {
            int q = r * 4 + wv;
            int row = q * 8 + srow8;
            gload_lds16((const char*)(w1t_h + (size_t)row * 256 + ki * 64 + swc * 8),
                        Bs_h + (q << 10));
            gload_lds16((const char*)(w1t_l + (size_t)row * 256 + ki * 64 + swc * 8),
                        Bs_l + (q << 10));
        }
        __syncthreads();
        #pragma unroll
        for (int kh = 0; kh < 2; kh++) {
            const int chunk = kgrp + 4 * kh;
            const int abyte = lane16 * 128 + ((chunk ^ (lane16 & 7)) << 4);
            bf16x8 ah = *(const bf16x8*)(As_h + abyte);
            bf16x8 al = *(const bf16x8*)(As_l + abyte);
            #pragma unroll
            for (int g = 0; g < 2; g++) {
                int brow = wv * 32 + (g << 4) + lane16;
                int bbyte = brow * 128 + ((chunk ^ (brow & 7)) << 4);
                bf16x8 bh = *(const bf16x8*)(Bs_h + bbyte);
                bf16x8 bl = *(const bf16x8*)(Bs_l + bbyte);
                acc1[g] = __builtin_amdgcn_mfma_f32_16x16x32_bf16(ah, bh, acc1[g], 0, 0, 0);
                acc1[g] = __builtin_amdgcn_mfma_f32_16x16x32_bf16(ah, bl, acc1[g], 0, 0, 0);
                acc1[g] = __builtin_amdgcn_mfma_f32_16x16x32_bf16(al, bh, acc1[g], 0, 0, 0);
            }
        }
        __syncthreads();
    }

    #pragma unroll
    for (int fc = 0; fc < 2; fc++) {
        int col = wv * 32 + (fc << 4) + lane16;
        float bcv = bc[col], b1v = b1[col], b2v = b2[col];
        #pragma unroll
        for (int j = 0; j < 4; j++) {
            int px = kgrp * 4 + j;
            size_t gp = (size_t)gblk * 16 + px;
            float core = acc[fc][j] + bcv;
            float g2 = acc[fc + 2][j] + b2v;
            float a1 = acc1[fc][j] + b1v;
            float s1 = 1.f / (1.f + expf(-a1));
            float s2 = 1.f / (1.f + expf(-g2));
            outp[gp * 128 + col] = 0.5f * (s1 + s2) * core;
        }
    }
}

extern "C" void kernel_launch(void* const* d_in, const int* in_sizes, int n_in,
                              void* d_out, int out_size, void* d_ws, size_t ws_size,
                              hipStream_t stream) {
    const float* x    = (const float*)d_in[0];
    const float* mask = (const float*)d_in[1];
    const float* Wc   = (const float*)d_in[2];
    const float* bc   = (const float*)d_in[3];
    const float* W1   = (const float*)d_in[4];
    const float* b1   = (const float*)d_in[5];
    const float* W2   = (const float*)d_in[6];
    const float* b2   = (const float*)d_in[7];
    float* outp = (float*)d_out;

    char* ws = (char*)d_ws;
    const size_t SZ_P  = (size_t)NPIX * KC;
    const size_t SZ_S  = (size_t)NPIX * NPIX;
    const size_t SZ_Y  = (size_t)NPIX * NPIX;
    const size_t SZ_O2 = (size_t)NPIX * KC;
    const size_t NEED_HUGE = 250020096UL;

    if (ws_size >= NEED_HUGE) {
        __hip_bfloat16* Pbf2  = (__hip_bfloat16*)(ws + 0);
        __hip_bfloat16* Pt2   = (__hip_bfloat16*)(ws + 18874368UL);
        float* S2             = (float*)(ws + 37748736UL);
        __hip_bfloat16* Y2    = (__hip_bfloat16*)(ws + 171966464UL);
        float* O2             = (float*)(ws + 37748736UL);   // aliases S2 (dead by then)
        __hip_bfloat16* ych   = (__hip_bfloat16*)(ws + 239075328UL);
        __hip_bfloat16* ycl   = (__hip_bfloat16*)(ws + 243269632UL);
        __hip_bfloat16* wtc_h = (__hip_bfloat16*)(ws + 247463936UL);
        __hip_bfloat16* wtc_l = (__hip_bfloat16*)(ws + 248053760UL);
        __hip_bfloat16* wt2_h = (__hip_bfloat16*)(ws + 248643584UL);
        __hip_bfloat16* wt2_l = (__hip_bfloat16*)(ws + 249233408UL);
        __hip_bfloat16* w1t_h = (__hip_bfloat16*)(ws + 249823232UL);
        __hip_bfloat16* w1t_l = (__hip_bfloat16*)(ws + 249888768UL);
        float* colnorm2       = (float*)(ws + 249954304UL);
        float* mmv2           = (float*)(ws + 249987072UL);
        float* zpage          = (float*)(ws + 250019840UL);

        hipLaunchKernelGGL(k_prep, dim3((2 * 128 * KF + 128 * 256 + 64 + 255) / 256),
                           dim3(256), 0, stream,
                           Wc, W2, W1, wtc_h, wtc_l, wt2_h, wt2_l, w1t_h, w1t_l, zpage);
        hipLaunchKernelGGL(k_build, dim3((2 * NPIX * KC) / 256, 2), dim3(256), 0, stream,
                           x, Pbf2, Pt2, SZ_P, SZ_P, 0);
        hipLaunchKernelGGL(k_normmm, dim3(NPIX, 2), dim3(256), 0, stream,
                           Pbf2, SZ_P, colnorm2, (size_t)NPIX, mask, mmv2, 0);
        hipLaunchKernelGGL(k_gemm_sym, dim3(528, 2), dim3(256), 0, stream,
                           Pbf2, S2, colnorm2, SZ_P, SZ_S, (size_t)NPIX);
        hipLaunchKernelGGL(k_fusesm, dim3(NPIX, 2), dim3(256), 0, stream,
                           S2, SZ_S, mmv2, (size_t)NPIX, Y2, SZ_Y);
        hipLaunchKernelGGL(k_mfma_gemm, dim3(9, 32, 2), dim3(256), 0, stream,
                           Y2, Pt2, O2, NPIX, KC, SZ_Y, SZ_P, SZ_O2);
        hipLaunchKernelGGL(k_deconv, dim3((2 * NPIX * CCH) / 256), dim3(256), 0, stream,
                           O2, x, ych, ycl, SZ_O2);
        hipLaunchKernelGGL(k_final_mfma, dim3(512), dim3(256), 0, stream,
                           ych, ycl, wtc_h, wtc_l, wt2_h, wt2_l, w1t_h, w1t_l,
                           bc, b1, b2, zpage, outp);
    } else {
        __hip_bfloat16* Pbf   = (__hip_bfloat16*)(ws + 0);
        __hip_bfloat16* Pt0   = (__hip_bfloat16*)(ws + 9437184UL);
        float* S              = (float*)(ws + 28311552UL);
        __hip_bfloat16* Y0    = (__hip_bfloat16*)(ws + 95420416UL);
        float* O2             = (float*)(ws + 162529280UL);
        __hip_bfloat16* ych   = (__hip_bfloat16*)(ws + 200278016UL);
        __hip_bfloat16* ycl   = (__hip_bfloat16*)(ws + 204472320UL);
        __hip_bfloat16* wtc_h = (__hip_bfloat16*)(ws + 208666624UL);
        __hip_bfloat16* wtc_l = (__hip_bfloat16*)(ws + 209256448UL);
        __hip_bfloat16* wt2_h = (__hip_bfloat16*)(ws + 209846272UL);
        __hip_bfloat16* wt2_l = (__hip_bfloat16*)(ws + 210436096UL);
        __hip_bfloat16* w1t_h = (__hip_bfloat16*)(ws + 211025920UL);
        __hip_bfloat16* w1t_l = (__hip_bfloat16*)(ws + 211091456UL);
        float* colnorm        = (float*)(ws + 211156992UL);
        float* mmv            = (float*)(ws + 211173376UL);
        float* zpage          = (float*)(ws + 211189760UL);

        hipLaunchKernelGGL(k_prep, dim3((2 * 128 * KF + 128 * 256 + 64 + 255) / 256),
                           dim3(256), 0, stream,
                           Wc, W2, W1, wtc_h, wtc_l, wt2_h, wt2_l, w1t_h, w1t_l, zpage);
        for (int b = 0; b < 2; b++) {
            hipLaunchKernelGGL(k_build, dim3((2 * NPIX * KC) / 256, 1), dim3(256), 0, stream,
                               x, Pbf, Pt0 + (size_t)b * SZ_P, (size_t)0, (size_t)0, b);
            hipLaunchKernelGGL(k_normmm, dim3(NPIX, 1), dim3(256), 0, stream,
                               Pbf, (size_t)0, colnorm, (size_t)0, mask, mmv, b);
            hipLaunchKernelGGL(k_gemm_sym, dim3(528, 1), dim3(256), 0, stream,
                               Pbf, S, colnorm, (size_t)0, (size_t)0, (size_t)0);
            hipLaunchKernelGGL(k_fusesm, dim3(NPIX, 1), dim3(256), 0, stream,
                               S, (size_t)0, mmv, (size_t)0, Y0 + (size_t)b * SZ_Y, (size_t)0);
        }
        hipLaunchKernelGGL(k_mfma_gemm, dim3(9, 32, 2), dim3(256), 0, stream,
                           Y0, Pt0, O2, NPIX, KC, SZ_Y, SZ_P, SZ_O2);
        hipLaunchKernelGGL(k_deconv, dim3((2 * NPIX * CCH) / 256), dim3(256), 0, stream,
                           O2, x, ych, ycl, SZ_O2);
        hipLaunchKernelGGL(k_final_mfma, dim3(512), dim3(256), 0, stream,
                           ych, ycl, wtc_h, wtc_l, wt2_h, wt2_l, w1t_h, w1t_l,
                           bc, b1, b2, zpage, outp);
    }
}

// Round 21
// 402.330 us; speedup vs baseline: 1.1497x; 1.1497x over previous
//
#include <hip/hip_runtime.h>
#include <hip/hip_bf16.h>
#include <math.h>

#define HW   64
#define NPIX 4096
#define CCH  128
#define KC   1152   // 9*C
#define KF   2304   // 9*256 (final conv K)
#define SCALEF 10.0f

typedef __attribute__((ext_vector_type(8))) short bf16x8;
typedef __attribute__((ext_vector_type(4))) float f32x4;
typedef __attribute__((ext_vector_type(4))) unsigned short u16x4;

__device__ inline void gload_lds16(const void* g, void* l) {
    __builtin_amdgcn_global_load_lds(
        (const __attribute__((address_space(1))) unsigned int*)g,
        (__attribute__((address_space(3))) unsigned int*)l, 16, 0, 0);
}

__device__ inline f32x4 ld4u(const float* p) {
    f32x4 v; __builtin_memcpy(&v, p, 16); return v;
}

// LDS tile layout (both GEMMs): slot (r,g) at byte r*64 + ((g ^ ((r>>1)&3))<<4).
// Staged via global_load_lds with PRE-SWIZZLED SOURCE (linear LDS dest, rule #21);
// read with the same involution -> conflict-free on both sides.
#define SWZ_OFF(r, g) ((r) * 64 + ((((g) ^ (((r) >> 1) & 3))) << 4))

// ---------------- build Pbf[n,1152] AND Pt[1152,4096]; batch via grid.y ----------
__global__ void k_build(const float* __restrict__ x, __hip_bfloat16* __restrict__ P,
                        __hip_bfloat16* __restrict__ Pt, size_t sP, size_t sPt, int b0) {
    const int b = b0 + blockIdx.y;
    P += (size_t)blockIdx.y * sP; Pt += (size_t)blockIdx.y * sPt;
    int idx = blockIdx.x * blockDim.x + threadIdx.x;
    if (idx < NPIX * KC) {
        int n = idx / KC, t = idx - n * KC;
        int u = t / 384, v = (t / 128) % 3, c = t & 127;
        int h = n >> 6, w = n & 63;
        int hh = h + u - 1, ww = w + v - 1;
        float val = 0.f;
        if (hh >= 0 && hh < HW && ww >= 0 && ww < HW)
            val = x[((size_t)(b * NPIX) + hh * HW + ww) * CCH + c];
        P[(size_t)n * KC + t] = __float2bfloat16(val);
    } else {
        int i2 = idx - NPIX * KC;
        int j = i2 >> 12, k = i2 & 4095;
        int u = j / 384, v = (j / 128) % 3, c = j & 127;
        int h = k >> 6, w = k & 63;
        int hh = h + u - 1, ww = w + v - 1;
        float val = 0.f;
        if (hh >= 0 && hh < HW && ww >= 0 && ww < HW)
            val = x[((size_t)(b * NPIX) + hh * HW + ww) * CCH + c];
        Pt[i2] = __float2bfloat16(val);
    }
}

// ---------------- per-patch norm + mask validity; batch via grid.y ----------------
__global__ void k_normmm(const __hip_bfloat16* __restrict__ P, size_t sP,
                         float* __restrict__ cn, size_t sCn,
                         const float* __restrict__ mask, float* __restrict__ mmv, int b0) {
    const int b = b0 + blockIdx.y;
    P += (size_t)blockIdx.y * sP; cn += (size_t)blockIdx.y * sCn;
    mmv += (size_t)blockIdx.y * sCn;
    int n = blockIdx.x;
    int tid = threadIdx.x;
    float s = 0.f;
    for (int t = tid; t < KC; t += 256) {
        float v = __bfloat162float(P[(size_t)n * KC + t]);
        s += v * v;
    }
    __shared__ float red[256];
    red[tid] = s; __syncthreads();
    for (int st = 128; st > 0; st >>= 1) {
        if (tid < st) red[tid] += red[tid + st];
        __syncthreads();
    }
    if (tid == 0) cn[n] = fmaxf(sqrtf(red[0]), 1e-4f);
    if (tid == 64) {
        int h = n >> 6, w = n & 63;
        float ms = 0.f;
        for (int u = 0; u < 3; u++)
            for (int v = 0; v < 3; v++) {
                int hh = h + u - 1, ww = w + v - 1;
                if (hh >= 0 && hh < HW && ww >= 0 && ww < HW)
                    ms += mask[(size_t)b * NPIX + hh * HW + ww];
            }
        mmv[n] = ((ms / 9.0f) == 1.0f) ? 1.0f : 0.0f;
    }
}

// ---------------- prep: zero page + all weight splits ----------------
__global__ void k_prep(const float* __restrict__ Wc, const float* __restrict__ W2,
                       const float* __restrict__ W1,
                       __hip_bfloat16* __restrict__ wtc_h, __hip_bfloat16* __restrict__ wtc_l,
                       __hip_bfloat16* __restrict__ wt2_h, __hip_bfloat16* __restrict__ wt2_l,
                       __hip_bfloat16* __restrict__ w1t_h, __hip_bfloat16* __restrict__ w1t_l,
                       float* __restrict__ zp) {
    int idx = blockIdx.x * blockDim.x + threadIdx.x;
    const int NWS = 2 * 128 * KF;
    if (idx < NWS) {
        int m = idx / (128 * KF);
        int rem = idx - m * 128 * KF;
        int j = rem / KF, k = rem - j * KF;
        const float* src = m ? W2 : Wc;
        float v = src[(size_t)k * 128 + j];
        __hip_bfloat16 hi = __float2bfloat16(v);
        __hip_bfloat16 lo = __float2bfloat16(v - __bfloat162float(hi));
        (m ? wt2_h : wtc_h)[(size_t)j * KF + k] = hi;
        (m ? wt2_l : wtc_l)[(size_t)j * KF + k] = lo;
    } else if (idx < NWS + 128 * 256) {
        int i2 = idx - NWS;
        int j = i2 >> 8, k = i2 & 255;
        float v = W1[(size_t)k * 128 + j];
        __hip_bfloat16 hi = __float2bfloat16(v);
        __hip_bfloat16 lo = __float2bfloat16(v - __bfloat162float(hi));
        w1t_h[(size_t)j * 256 + k] = hi;
        w1t_l[(size_t)j * 256 + k] = lo;
    } else if (idx < NWS + 128 * 256 + 64) {
        zp[idx - NWS - 128 * 256] = 0.f;
    }
}

// ---------------- GEMM1 symmetric: upper-triangle tiles, BK=32, preswz gload -----
__global__ __launch_bounds__(256) void k_gemm_sym(
    const __hip_bfloat16* __restrict__ A, float* __restrict__ C,
    const float* __restrict__ colnorm, size_t sA, size_t sC, size_t sCn) {
    __shared__ __align__(16) __hip_bfloat16 As[2][128 * 32];
    __shared__ __align__(16) __hip_bfloat16 Bs[2][128 * 32];
    A += (size_t)blockIdx.y * sA; C += (size_t)blockIdx.y * sC;
    colnorm += (size_t)blockIdx.y * sCn;
    const int tid = threadIdx.x;
    const int l = tid & 63;
    const int wid = tid >> 6;
    const int wr = wid >> 1, wc = wid & 1;
    const int lane16 = l & 15, kgrp = l >> 4;
    const int id0 = blockIdx.x;
    int t = (id0 & 7) * 66 + (id0 >> 3);
    int ti = 0;
    while (t >= 32 - ti) { t -= 32 - ti; ti++; }
    const int tj = ti + t;
    const int p0 = ti * 128, q0 = tj * 128;
    const int lr = l >> 2;
    const int lc = l & 3;

    f32x4 acc[16];
    f32x4 zf; zf[0] = 0.f; zf[1] = 0.f; zf[2] = 0.f; zf[3] = 0.f;
    #pragma unroll
    for (int i = 0; i < 16; i++) acc[i] = zf;

    auto stage = [&](int buf, int k0) {
        #pragma unroll
        for (int tt = 0; tt < 2; tt++) {
            int r0 = wid * 32 + tt * 16;
            int gr = r0 + lr;
            int sc = (lc ^ ((gr >> 1) & 3)) * 8;
            gload_lds16(A + (size_t)(p0 + gr) * KC + k0 + sc,
                        (char*)As[buf] + r0 * 64);
            gload_lds16(A + (size_t)(q0 + gr) * KC + k0 + sc,
                        (char*)Bs[buf] + r0 * 64);
        }
    };

    const int nst = KC >> 5;
    stage(0, 0);
    __syncthreads();
    int cur = 0;
    for (int s = 0; s < nst; ++s) {
        if (s + 1 < nst) stage(cur ^ 1, (s + 1) << 5);
        const char* Ab = (const char*)As[cur];
        const char* Bb = (const char*)Bs[cur];
        bf16x8 af[4], bg[4];
        #pragma unroll
        for (int mi = 0; mi < 4; mi++) {
            int row = wr * 64 + mi * 16 + lane16;
            af[mi] = *(const bf16x8*)(Ab + SWZ_OFF(row, kgrp));
        }
        #pragma unroll
        for (int ni = 0; ni < 4; ni++) {
            int row = wc * 64 + ni * 16 + lane16;
            bg[ni] = *(const bf16x8*)(Bb + SWZ_OFF(row, kgrp));
        }
        #pragma unroll
        for (int mi = 0; mi < 4; mi++)
            #pragma unroll
            for (int ni = 0; ni < 4; ni++)
                acc[mi * 4 + ni] = __builtin_amdgcn_mfma_f32_16x16x32_bf16(
                    af[mi], bg[ni], acc[mi * 4 + ni], 0, 0, 0);
        __syncthreads();
        cur ^= 1;
    }

    float invq[4];
    #pragma unroll
    for (int ni = 0; ni < 4; ni++)
        invq[ni] = 1.0f / colnorm[q0 + wc * 64 + ni * 16 + lane16];
    float invp[4][4];
    #pragma unroll
    for (int mi = 0; mi < 4; mi++) {
        int rbase = p0 + wr * 64 + mi * 16 + kgrp * 4;
        #pragma unroll
        for (int j = 0; j < 4; j++)
            invp[mi][j] = 1.0f / colnorm[rbase + j];
    }
    #pragma unroll
    for (int mi = 0; mi < 4; mi++) {
        int rbase = p0 + wr * 64 + mi * 16 + kgrp * 4;
        #pragma unroll
        for (int ni = 0; ni < 4; ni++) {
            int col = q0 + wc * 64 + ni * 16 + lane16;
            f32x4 v = acc[mi * 4 + ni];
            #pragma unroll
            for (int j = 0; j < 4; j++)
                C[(size_t)(rbase + j) * NPIX + col] = v[j] * invq[ni];
            if (ti != tj) {
                float4 tv;
                tv.x = v[0] * invp[mi][0]; tv.y = v[1] * invp[mi][1];
                tv.z = v[2] * invp[mi][2]; tv.w = v[3] * invp[mi][3];
                *(float4*)&C[(size_t)col * NPIX + rbase] = tv;
            }
        }
    }
}

// ---------------- GEMM2: 128x128, BK=32, preswz gload, batch-z -------------------
__global__ __launch_bounds__(256) void k_mfma_gemm(
    const __hip_bfloat16* __restrict__ A, const __hip_bfloat16* __restrict__ B,
    float* __restrict__ C, int Ka, int ldc, size_t sA, size_t sB, size_t sC) {
    __shared__ __align__(16) __hip_bfloat16 As[2][128 * 32];
    __shared__ __align__(16) __hip_bfloat16 Bs[2][128 * 32];
    const int zb = blockIdx.z;
    A += (size_t)zb * sA; B += (size_t)zb * sB; C += (size_t)zb * sC;
    const int tid = threadIdx.x;
    const int l = tid & 63;
    const int wid = tid >> 6;
    const int wr = wid >> 1, wc = wid & 1;
    const int lane16 = l & 15, kgrp = l >> 4;
    const int gx = gridDim.x;
    const int nwg = gx * gridDim.y;
    const int id0 = blockIdx.y * gx + blockIdx.x;
    const int swzid = (id0 & 7) * (nwg >> 3) + (id0 >> 3);
    const int p0 = (swzid / gx) * 128, q0 = (swzid % gx) * 128;
    const int lr = l >> 2;
    const int lc = l & 3;

    f32x4 acc[16];
    f32x4 zf; zf[0] = 0.f; zf[1] = 0.f; zf[2] = 0.f; zf[3] = 0.f;
    #pragma unroll
    for (int i = 0; i < 16; i++) acc[i] = zf;

    auto stage = [&](int buf, int k0) {
        #pragma unroll
        for (int tt = 0; tt < 2; tt++) {
            int r0 = wid * 32 + tt * 16;
            int gr = r0 + lr;
            int sc = (lc ^ ((gr >> 1) & 3)) * 8;
            gload_lds16(A + (size_t)(p0 + gr) * Ka + k0 + sc,
                        (char*)As[buf] + r0 * 64);
            gload_lds16(B + (size_t)(q0 + gr) * Ka + k0 + sc,
                        (char*)Bs[buf] + r0 * 64);
        }
    };

    const int nst = Ka >> 5;
    stage(0, 0);
    __syncthreads();
    int cur = 0;
    for (int s = 0; s < nst; ++s) {
        if (s + 1 < nst) stage(cur ^ 1, (s + 1) << 5);
        const char* Ab = (const char*)As[cur];
        const char* Bb = (const char*)Bs[cur];
        bf16x8 af[4], bg[4];
        #pragma unroll
        for (int mi = 0; mi < 4; mi++) {
            int row = wr * 64 + mi * 16 + lane16;
            af[mi] = *(const bf16x8*)(Ab + SWZ_OFF(row, kgrp));
        }
        #pragma unroll
        for (int ni = 0; ni < 4; ni++) {
            int row = wc * 64 + ni * 16 + lane16;
            bg[ni] = *(const bf16x8*)(Bb + SWZ_OFF(row, kgrp));
        }
        #pragma unroll
        for (int mi = 0; mi < 4; mi++)
            #pragma unroll
            for (int ni = 0; ni < 4; ni++)
                acc[mi * 4 + ni] = __builtin_amdgcn_mfma_f32_16x16x32_bf16(
                    af[mi], bg[ni], acc[mi * 4 + ni], 0, 0, 0);
        __syncthreads();
        cur ^= 1;
    }

    #pragma unroll
    for (int mi = 0; mi < 4; mi++) {
        int rbase = p0 + wr * 64 + mi * 16 + kgrp * 4;
        #pragma unroll
        for (int ni = 0; ni < 4; ni++) {
            int col = q0 + wc * 64 + ni * 16 + lane16;
            f32x4 v = acc[mi * 4 + ni];
            #pragma unroll
            for (int j = 0; j < 4; j++)
                C[(size_t)(rbase + j) * ldc + col] = v[j];
        }
    }
}

// ---------------- fuse + mask + softmax; shuffle reductions; batch via grid.y ----
__global__ __launch_bounds__(256) void k_fusesm(const float* __restrict__ S, size_t sS,
                                                const float* __restrict__ mmv, size_t sM,
                                                __hip_bfloat16* __restrict__ Y, size_t sY) {
    S += (size_t)blockIdx.y * sS; mmv += (size_t)blockIdx.y * sM;
    Y += (size_t)blockIdx.y * sY;
    int blk = blockIdx.x;
    int p = ((blk & 7) << 9) | (blk >> 3);
    int tid = threadIdx.x;
    __shared__ float wredA[4], wredB[4];
    int cmp = ((p & 63) << 6) | (p >> 6);
    const float* rowp[3][3];
    #pragma unroll
    for (int ei = 0; ei < 3; ei++)
        #pragma unroll
        for (int di = 0; di < 3; di++) {
            int cp2 = cmp + ei - 1;
            const float* rp = nullptr;
            if (cp2 >= 0 && cp2 < NPIX) {
                int prm = ((cp2 & 63) << 6) | (cp2 >> 6);
                int pa = prm + di - 1;
                if (pa >= 0 && pa < NPIX) rp = S + (size_t)pa * NPIX;
            }
            rowp[ei][di] = rp;
        }

    f32x4 zv[4];
    float lmax = -1e30f;
    #pragma unroll
    for (int qi = 0; qi < 4; qi++) {
        const int q0 = (qi << 10) + (tid << 2);
        f32x4 acc; acc[0] = 0.f; acc[1] = 0.f; acc[2] = 0.f; acc[3] = 0.f;
        if (q0 >= 68 && q0 <= 4024) {
            #pragma unroll
            for (int ei = 0; ei < 3; ei++)
                #pragma unroll
                for (int di = 0; di < 3; di++) {
                    const float* rp = rowp[ei][di];
                    if (!rp) continue;
                    f32x4 v = ld4u(rp + q0 + (ei - 1) * 64 + (di - 1));
                    acc[0] += v[0]; acc[1] += v[1]; acc[2] += v[2]; acc[3] += v[3];
                }
        } else {
            #pragma unroll
            for (int j = 0; j < 4; j++) {
                int q = q0 + j;
                int cmq = ((q & 63) << 6) | (q >> 6);
                float a = 0.f;
                #pragma unroll
                for (int ei = 0; ei < 3; ei++) {
                    int cq2 = cmq + ei - 1;
                    if (cq2 < 0 || cq2 >= NPIX) continue;
                    int qrm = ((cq2 & 63) << 6) | (cq2 >> 6);
                    #pragma unroll
                    for (int di = 0; di < 3; di++) {
                        int qa = qrm + di - 1;
                        const float* rp = rowp[ei][di];
                        if (rp && qa >= 0 && qa < NPIX) a += rp[qa];
                    }
                }
                acc[j] = a;
            }
        }
        f32x4 m4 = *(const f32x4*)(mmv + q0);
        #pragma unroll
        for (int j = 0; j < 4; j++) {
            float zz = acc[j] * m4[j] * SCALEF;
            zv[qi][j] = zz;
            lmax = fmaxf(lmax, zz);
        }
    }

    #pragma unroll
    for (int off = 32; off >= 1; off >>= 1)
        lmax = fmaxf(lmax, __shfl_xor(lmax, off, 64));
    if ((tid & 63) == 0) wredA[tid >> 6] = lmax;
    __syncthreads();
    float gmax = fmaxf(fmaxf(wredA[0], wredA[1]), fmaxf(wredA[2], wredA[3]));

    float lsum = 0.f;
    #pragma unroll
    for (int qi = 0; qi < 4; qi++)
        #pragma unroll
        for (int j = 0; j < 4; j++) {
            float e = __expf(zv[qi][j] - gmax);
            zv[qi][j] = e;
            lsum += e;
        }
    #pragma unroll
    for (int off = 32; off >= 1; off >>= 1)
        lsum += __shfl_xor(lsum, off, 64);
    if ((tid & 63) == 0) wredB[tid >> 6] = lsum;
    __syncthreads();
    float invs = 1.0f / (((wredB[0] + wredB[1]) + (wredB[2] + wredB[3])));

    #pragma unroll
    for (int qi = 0; qi < 4; qi++) {
        const int q0 = (qi << 10) + (tid << 2);
        f32x4 m4 = *(const f32x4*)(mmv + q0);
        __hip_bfloat16 tmp[4];
        #pragma unroll
        for (int j = 0; j < 4; j++)
            tmp[j] = __float2bfloat16(zv[qi][j] * invs * m4[j]);
        *(ushort4*)(Y + (size_t)p * NPIX + q0) = *(ushort4*)tmp;
    }
}

// ---------------- deconv gather (vectorized: 4 channels/thread) + concat x -------
__global__ void k_deconv(const float* __restrict__ O2, const float* __restrict__ x,
                         __hip_bfloat16* __restrict__ ych, __hip_bfloat16* __restrict__ ycl,
                         size_t sO2) {
    int idx = blockIdx.x * blockDim.x + threadIdx.x;   // 2*NPIX*CCH/4 threads
    int b = idx >> 17;
    int loc = idx & ((1 << 17) - 1);
    int p = loc >> 5, c4 = (loc & 31) << 2;            // c4 = 0,4,...,124
    int h = p >> 6, w = p & 63;
    const float* O2b = O2 + (size_t)b * sO2;
    f32x4 acc; acc[0] = 0.f; acc[1] = 0.f; acc[2] = 0.f; acc[3] = 0.f;
    #pragma unroll
    for (int u = 0; u < 3; u++) {
        int hh = h + 1 - u;
        if (hh < 0 || hh >= HW) continue;
        #pragma unroll
        for (int v = 0; v < 3; v++) {
            int ww = w + 1 - v;
            if (ww < 0 || ww >= HW) continue;
            f32x4 t = *(const f32x4*)(O2b + (size_t)(hh * HW + ww) * KC
                                      + (u * 3 + v) * CCH + c4);
            acc[0] += t[0]; acc[1] += t[1]; acc[2] += t[2]; acc[3] += t[3];
        }
    }
    f32x4 xv = *(const f32x4*)(x + ((size_t)b * NPIX + p) * CCH + c4);
    size_t base = (size_t)b * NPIX * 256 + (size_t)p * 256;
    u16x4 ah, al, xh, xl;
    #pragma unroll
    for (int j = 0; j < 4; j++) {
        __hip_bfloat16 hb = __float2bfloat16(acc[j]);
        __hip_bfloat16 lb = __float2bfloat16(acc[j] - __bfloat162float(hb));
        ah[j] = *(unsigned short*)&hb; al[j] = *(unsigned short*)&lb;
        __hip_bfloat16 hx = __float2bfloat16(xv[j]);
        __hip_bfloat16 lx = __float2bfloat16(xv[j] - __bfloat162float(hx));
        xh[j] = *(unsigned short*)&hx; xl[j] = *(unsigned short*)&lx;
    }
    *(u16x4*)(ych + base + c4)       = ah;
    *(u16x4*)(ych + base + 128 + c4) = xh;
    *(u16x4*)(ycl + base + c4)       = al;
    *(u16x4*)(ycl + base + 128 + c4) = xl;
}

// ---------------- final conv via split-bf16 MFMA, W1 gate folded in ----------------
__global__ __launch_bounds__(256) void k_final_mfma(
    const __hip_bfloat16* __restrict__ ych, const __hip_bfloat16* __restrict__ ycl,
    const __hip_bfloat16* __restrict__ wtc_h, const __hip_bfloat16* __restrict__ wtc_l,
    const __hip_bfloat16* __restrict__ wt2_h, const __hip_bfloat16* __restrict__ wt2_l,
    const __hip_bfloat16* __restrict__ w1t_h, const __hip_bfloat16* __restrict__ w1t_l,
    const float* __restrict__ bc, const float* __restrict__ b1,
    const float* __restrict__ b2, const float* __restrict__ zpage,
    float* __restrict__ outp) {
    __shared__ __align__(16) char As_h[2048], As_l[2048];
    __shared__ __align__(16) char Bs_h[32768], Bs_l[32768];
    const int tid = threadIdx.x;
    const int lane = tid & 63, wv = tid >> 6;
    const int lane16 = lane & 15, kgrp = lane >> 4;
    const int gblk = blockIdx.x;
    const int b = gblk >> 8;
    const int p0l = (gblk & 255) * 16;
    const __hip_bfloat16* ybh = ych + (size_t)b * NPIX * 256;
    const __hip_bfloat16* ybl = ycl + (size_t)b * NPIX * 256;
    const int srow8 = lane >> 3;
    const int c16 = lane & 7;
    const int swc = c16 ^ srow8;

    const int arow = ((wv & 1) << 3) + srow8;
    const int apr = p0l + arow;
    const int ah_ = apr >> 6, aw_ = apr & 63;
    char* const a_ldst = ((wv >> 1) ? As_l : As_h) + ((wv & 1) << 10);
    const __hip_bfloat16* const a_base = (wv >> 1) ? ybl : ybh;

    const char* bsrc_h[8];
    const char* bsrc_l[8];
    #pragma unroll
    for (int r = 0; r < 8; r++) {
        int q = r * 4 + wv;
        int row = q * 8 + srow8;
        const __hip_bfloat16* mh = (row < 128) ? (wtc_h + (size_t)row * KF)
                                               : (wt2_h + (size_t)(row - 128) * KF);
        const __hip_bfloat16* ml = (row < 128) ? (wtc_l + (size_t)row * KF)
                                               : (wt2_l + (size_t)(row - 128) * KF);
        bsrc_h[r] = (const char*)(mh + swc * 8);
        bsrc_l[r] = (const char*)(ml + swc * 8);
    }

    f32x4 acc[4];
    f32x4 zf; zf[0] = 0.f; zf[1] = 0.f; zf[2] = 0.f; zf[3] = 0.f;
    #pragma unroll
    for (int f = 0; f < 4; f++) acc[f] = zf;

    for (int it = 0; it < 36; ++it) {
        const int k0 = it * 64;
        const int tap = k0 >> 8, i0 = k0 & 255;
        const int di = tap / 3, dj = tap - di * 3;
        {
            int hh = ah_ + di - 1, ww = aw_ + dj - 1;
            const void* src;
            if (hh >= 0 && hh < HW && ww >= 0 && ww < HW)
                src = a_base + ((size_t)(hh * HW + ww) * 256 + i0 + swc * 8);
            else
                src = (const char*)zpage + c16 * 16;
            gload_lds16(src, a_ldst);
        }
        #pragma unroll
        for (int r = 0; r < 8; r++) {
            int q = r * 4 + wv;
            gload_lds16(bsrc_h[r] + (size_t)it * 128, Bs_h + (q << 10));
            gload_lds16(bsrc_l[r] + (size_t)it * 128, Bs_l + (q << 10));
        }
        __syncthreads();
        #pragma unroll
        for (int kh = 0; kh < 2; kh++) {
            const int chunk = kgrp + 4 * kh;
            const int abyte = lane16 * 128 + ((chunk ^ (lane16 & 7)) << 4);
            bf16x8 ah = *(const bf16x8*)(As_h + abyte);
            bf16x8 al = *(const bf16x8*)(As_l + abyte);
            #pragma unroll
            for (int f = 0; f < 4; f++) {
                int brow = ((f < 2) ? 0 : 128) + wv * 32 + ((f & 1) << 4) + lane16;
                int bbyte = brow * 128 + ((chunk ^ (brow & 7)) << 4);
                bf16x8 bh = *(const bf16x8*)(Bs_h + bbyte);
                bf16x8 bl = *(const bf16x8*)(Bs_l + bbyte);
                acc[f] = __builtin_amdgcn_mfma_f32_16x16x32_bf16(ah, bh, acc[f], 0, 0, 0);
                acc[f] = __builtin_amdgcn_mfma_f32_16x16x32_bf16(ah, bl, acc[f], 0, 0, 0);
                acc[f] = __builtin_amdgcn_mfma_f32_16x16x32_bf16(al, bh, acc[f], 0, 0, 0);
            }
        }
        __syncthreads();
    }

    f32x4 acc1[2];
    acc1[0] = zf; acc1[1] = zf;
    for (int ki = 0; ki < 4; ++ki) {
        gload_lds16(a_base + ((size_t)(ah_ * HW + aw_) * 256 + ki * 64 + swc * 8), a_ldst);
        #pragma unroll
        for (int r = 0; r < 4; r++) {
            int q = r * 4 + wv;
            int row = q * 8 + srow8;
            gload_lds16((const char*)(w1t_h + (size_t)row * 256 + ki * 64 + swc * 8),
                        Bs_h + (q << 10));
            gload_lds16((const char*)(w1t_l + (size_t)row * 256 + ki * 64 + swc * 8),
                        Bs_l + (q << 10));
        }
        __syncthreads();
        #pragma unroll
        for (int kh = 0; kh < 2; kh++) {
            const int chunk = kgrp + 4 * kh;
            const int abyte = lane16 * 128 + ((chunk ^ (lane16 & 7)) << 4);
            bf16x8 ah = *(const bf16x8*)(As_h + abyte);
            bf16x8 al = *(const bf16x8*)(As_l + abyte);
            #pragma unroll
            for (int g = 0; g < 2; g++) {
                int brow = wv * 32 + (g << 4) + lane16;
                int bbyte = brow * 128 + ((chunk ^ (brow & 7)) << 4);
                bf16x8 bh = *(const bf16x8*)(Bs_h + bbyte);
                bf16x8 bl = *(const bf16x8*)(Bs_l + bbyte);
                acc1[g] = __builtin_amdgcn_mfma_f32_16x16x32_bf16(ah, bh, acc1[g], 0, 0, 0);
                acc1[g] = __builtin_amdgcn_mfma_f32_16x16x32_bf16(ah, bl, acc1[g], 0, 0, 0);
                acc1[g] = __builtin_amdgcn_mfma_f32_16x16x32_bf16(al, bh, acc1[g], 0, 0, 0);
            }
        }
        __syncthreads();
    }

    #pragma unroll
    for (int fc = 0; fc < 2; fc++) {
        int col = wv * 32 + (fc << 4) + lane16;
        float bcv = bc[col], b1v = b1[col], b2v = b2[col];
        #pragma unroll
        for (int j = 0; j < 4; j++) {
            int px = kgrp * 4 + j;
            size_t gp = (size_t)gblk * 16 + px;
            float core = acc[fc][j] + bcv;
            float g2 = acc[fc + 2][j] + b2v;
            float a1 = acc1[fc][j] + b1v;
            float s1 = 1.f / (1.f + expf(-a1));
            float s2 = 1.f / (1.f + expf(-g2));
            outp[gp * 128 + col] = 0.5f * (s1 + s2) * core;
        }
    }
}

extern "C" void kernel_launch(void* const* d_in, const int* in_sizes, int n_in,
                              void* d_out, int out_size, void* d_ws, size_t ws_size,
                              hipStream_t stream) {
    const float* x    = (const float*)d_in[0];
    const float* mask = (const float*)d_in[1];
    const float* Wc   = (const float*)d_in[2];
    const float* bc   = (const float*)d_in[3];
    const float* W1   = (const float*)d_in[4];
    const float* b1   = (const float*)d_in[5];
    const float* W2   = (const float*)d_in[6];
    const float* b2   = (const float*)d_in[7];
    float* outp = (float*)d_out;

    char* ws = (char*)d_ws;
    const size_t SZ_P  = (size_t)NPIX * KC;
    const size_t SZ_S  = (size_t)NPIX * NPIX;
    const size_t SZ_Y  = (size_t)NPIX * NPIX;
    const size_t SZ_O2 = (size_t)NPIX * KC;
    const size_t NEED_HUGE = 250020096UL;

    if (ws_size >= NEED_HUGE) {
        __hip_bfloat16* Pbf2  = (__hip_bfloat16*)(ws + 0);
        __hip_bfloat16* Pt2   = (__hip_bfloat16*)(ws + 18874368UL);
        float* S2             = (float*)(ws + 37748736UL);
        __hip_bfloat16* Y2    = (__hip_bfloat16*)(ws + 171966464UL);
        float* O2             = (float*)(ws + 37748736UL);   // aliases S2 (dead by then)
        __hip_bfloat16* ych   = (__hip_bfloat16*)(ws + 239075328UL);
        __hip_bfloat16* ycl   = (__hip_bfloat16*)(ws + 243269632UL);
        __hip_bfloat16* wtc_h = (__hip_bfloat16*)(ws + 247463936UL);
        __hip_bfloat16* wtc_l = (__hip_bfloat16*)(ws + 248053760UL);
        __hip_bfloat16* wt2_h = (__hip_bfloat16*)(ws + 248643584UL);
        __hip_bfloat16* wt2_l = (__hip_bfloat16*)(ws + 249233408UL);
        __hip_bfloat16* w1t_h = (__hip_bfloat16*)(ws + 249823232UL);
        __hip_bfloat16* w1t_l = (__hip_bfloat16*)(ws + 249888768UL);
        float* colnorm2       = (float*)(ws + 249954304UL);
        float* mmv2           = (float*)(ws + 249987072UL);
        float* zpage          = (float*)(ws + 250019840UL);

        hipLaunchKernelGGL(k_prep, dim3((2 * 128 * KF + 128 * 256 + 64 + 255) / 256),
                           dim3(256), 0, stream,
                           Wc, W2, W1, wtc_h, wtc_l, wt2_h, wt2_l, w1t_h, w1t_l, zpage);
        hipLaunchKernelGGL(k_build, dim3((2 * NPIX * KC) / 256, 2), dim3(256), 0, stream,
                           x, Pbf2, Pt2, SZ_P, SZ_P, 0);
        hipLaunchKernelGGL(k_normmm, dim3(NPIX, 2), dim3(256), 0, stream,
                           Pbf2, SZ_P, colnorm2, (size_t)NPIX, mask, mmv2, 0);
        hipLaunchKernelGGL(k_gemm_sym, dim3(528, 2), dim3(256), 0, stream,
                           Pbf2, S2, colnorm2, SZ_P, SZ_S, (size_t)NPIX);
        hipLaunchKernelGGL(k_fusesm, dim3(NPIX, 2), dim3(256), 0, stream,
                           S2, SZ_S, mmv2, (size_t)NPIX, Y2, SZ_Y);
        hipLaunchKernelGGL(k_mfma_gemm, dim3(9, 32, 2), dim3(256), 0, stream,
                           Y2, Pt2, O2, NPIX, KC, SZ_Y, SZ_P, SZ_O2);
        hipLaunchKernelGGL(k_deconv, dim3((2 * NPIX * CCH / 4) / 256), dim3(256), 0, stream,
                           O2, x, ych, ycl, SZ_O2);
        hipLaunchKernelGGL(k_final_mfma, dim3(512), dim3(256), 0, stream,
                           ych, ycl, wtc_h, wtc_l, wt2_h, wt2_l, w1t_h, w1t_l,
                           bc, b1, b2, zpage, outp);
    } else {
        __hip_bfloat16* Pbf   = (__hip_bfloat16*)(ws + 0);
        __hip_bfloat16* Pt0   = (__hip_bfloat16*)(ws + 9437184UL);
        float* S              = (float*)(ws + 28311552UL);
        __hip_bfloat16* Y0    = (__hip_bfloat16*)(ws + 95420416UL);
        float* O2             = (float*)(ws + 162529280UL);
        __hip_bfloat16* ych   = (__hip_bfloat16*)(ws + 200278016UL);
        __hip_bfloat16* ycl   = (__hip_bfloat16*)(ws + 204472320UL);
        __hip_bfloat16* wtc_h = (__hip_bfloat16*)(ws + 208666624UL);
        __hip_bfloat16* wtc_l = (__hip_bfloat16*)(ws + 209256448UL);
        __hip_bfloat16* wt2_h = (__hip_bfloat16*)(ws + 209846272UL);
        __hip_bfloat16* wt2_l = (__hip_bfloat16*)(ws + 210436096UL);
        __hip_bfloat16* w1t_h = (__hip_bfloat16*)(ws + 211025920UL);
        __hip_bfloat16* w1t_l = (__hip_bfloat16*)(ws + 211091456UL);
        float* colnorm        = (float*)(ws + 211156992UL);
        float* mmv            = (float*)(ws + 211173376UL);
        float* zpage          = (float*)(ws + 211189760UL);

        hipLaunchKernelGGL(k_prep, dim3((2 * 128 * KF + 128 * 256 + 64 + 255) / 256),
                           dim3(256), 0, stream,
                           Wc, W2, W1, wtc_h, wtc_l, wt2_h, wt2_l, w1t_h, w1t_l, zpage);
        for (int b = 0; b < 2; b++) {
            hipLaunchKernelGGL(k_build, dim3((2 * NPIX * KC) / 256, 1), dim3(256), 0, stream,
                               x, Pbf, Pt0 + (size_t)b * SZ_P, (size_t)0, (size_t)0, b);
            hipLaunchKernelGGL(k_normmm, dim3(NPIX, 1), dim3(256), 0, stream,
                               Pbf, (size_t)0, colnorm, (size_t)0, mask, mmv, b);
            hipLaunchKernelGGL(k_gemm_sym, dim3(528, 1), dim3(256), 0, stream,
                               Pbf, S, colnorm, (size_t)0, (size_t)0, (size_t)0);
            hipLaunchKernelGGL(k_fusesm, dim3(NPIX, 1), dim3(256), 0, stream,
                               S, (size_t)0, mmv, (size_t)0, Y0 + (size_t)b * SZ_Y, (size_t)0);
        }
        hipLaunchKernelGGL(k_mfma_gemm, dim3(9, 32, 2), dim3(256), 0, stream,
                           Y0, Pt0, O2, NPIX, KC, SZ_Y, SZ_P, SZ_O2);
        hipLaunchKernelGGL(k_deconv, dim3((2 * NPIX * CCH / 4) / 256), dim3(256), 0, stream,
                           O2, x, ych, ycl, SZ_O2);
        hipLaunchKernelGGL(k_final_mfma, dim3(512), dim3(256), 0, stream,
                           ych, ycl, wtc_h, wtc_l, wt2_h, wt2_l, w1t_h, w1t_l,
                           bc, b1, b2, zpage, outp);
    }
}